// Round 1
// baseline (805.722 us; speedup 1.0000x reference)
//
#include <hip/hip_runtime.h>

// ---------------------------------------------------------------------------
// SphericalHarmonicsShellsConv  (MI355X / gfx950)
//
// Per (b,v):  G(32x256) gathered rows -> y = K^T G (30x256) -> CG recombine
// Outputs: 4 tensors (B,V,2J+1,W_J), W = {160,336,384,320}, concatenated flat.
//
// Structure:
//   init_kernel (28 blocks): fp64 port of _su2_cg/_q_real_to_complex builds
//     the 27 real-CG tables (3269 floats) + a 1.0 slot + 1332 job descriptors
//     into d_ws. Runs every launch (graph-safe, ~µs).
//   conv_kernel (8192 blocks x 256):
//     phase 0: gather G into LDS (float4, coalesced)
//     phase 1: GEMM, thread = 1 column x 30 rows; K via uniform (scalar) loads
//     phase 2: y -> LDS (stride 260 to de-alias banks)
//     phase 3: job loop: out[j] = sum_nm CG * y[...]  (float4 per job)
// ---------------------------------------------------------------------------

#define NB      4
#define NN      4096
#define NV      2048
#define NP      32
#define NCH     256
#define NY      30
#define YS      260          // padded row stride for y in LDS
#define NJOBS   1332
#define CG_ONE  3269         // index of the constant 1.0 slot
#define CG_FLOATS 3270
#define JOBS_BYTE_OFF 13088  // 3270*4 -> aligned to 16

// ---- term tables (34 terms; see derivation in journal) ---------------------
// cg = -1: l0 copy (j=J,l=0); cg = -2: j0 copy (j=0,l=J); else offset in cgws
__device__ const int T_J[34]  = {0,0,0,0, 1,1,1,1,1,1,1,1,1, 2,2,2,2,2,2,2,2,2,2,2, 3,3,3,3,3,3,3,3,3,3};
__device__ const int T_j[34]  = {0,1,2,3, 1,0,1,2,1,2,3,2,3, 2,0,1,2,3,1,2,3,1,2,3, 3,0,2,3,1,2,3,1,2,3};
__device__ const int T_l[34]  = {0,1,2,3, 0,1,1,1,2,2,2,3,3, 0,2,1,1,1,2,2,2,3,3,3, 0,3,1,1,2,2,2,3,3,3};
__device__ const int T_ch[34] = {0,64,112,144, 0,48,112,160,192,240,272,288,320,
                                 0,32,96,144,176,192,240,272,288,336,368,
                                 0,16,80,112,128,176,208,224,272,304};
__device__ const int T_cg[34] = {-1,0,9,34, -1,-2,83,110,155,200,275,380,485,
                                 -1,-2,632,677,752,857,932,1057,1232,1337,1512,
                                 -1,-2,1757,1862,2009,2114,2289,2534,2681,2926};

__device__ const int YOFF[4] = {0, 4, 13, 23};
__device__ const int COFF[4] = {0, 16, 64, 144};
__device__ const int WTAB[4] = {160, 336, 384, 320};
__device__ const int STAB[4] = {160, 1008, 1920, 2240};            // (2J+1)*W
__device__ const int OTAB[4] = {0, 1310720, 9568256, 25296896};    // output bases

// ---------------------------------------------------------------------------
__device__ double dfact(int n) {
    double r = 1.0;
    for (int i = 2; i <= n; ++i) r *= (double)i;
    return r;
}

__device__ double su2cg(int j1, int m1, int j2, int m2, int j3, int m3) {
    // verbatim port of _su2_cg (m3 == m1+m2 guaranteed by caller)
    int vmin = -j1 + j2 + m3;
    if (-j1 + m1 > vmin) vmin = -j1 + m1;
    if (0 > vmin) vmin = 0;
    int vmax = j2 + j3 + m1;
    if (j3 - j1 + j2 < vmax) vmax = j3 - j1 + j2;
    if (j3 + m3 < vmax) vmax = j3 + m3;
    double Cc = sqrt((2.0 * j3 + 1.0) * dfact(j3 + j1 - j2) * dfact(j3 - j1 + j2) *
                     dfact(j1 + j2 - j3) * dfact(j3 + m3) * dfact(j3 - m3) /
                     (dfact(j1 + j2 + j3 + 1) * dfact(j1 - m1) * dfact(j1 + m1) *
                      dfact(j2 - m2) * dfact(j2 + m2)));
    double S = 0.0;
    for (int v = vmin; v <= vmax; ++v) {
        double t = dfact(j2 + j3 + m1 - v) * dfact(j1 - m1 + v) /
                   (dfact(v) * dfact(j3 - j1 + j2 - v) * dfact(j3 + m3 - v) *
                    dfact(v + j1 - j2 - m3));
        S += ((v + j2 + m2) & 1) ? -t : t;
    }
    return Cc * S;
}

// element [row][col] of (-i)^l * q_real_to_complex(l)
__device__ void qelem(int l, int row, int col, double* pre, double* pim) {
    int m = row - l;
    const double s2 = 0.70710678118654752440;
    double qr = 0.0, qi = 0.0;
    if (m < 0) {
        if (col == l - m) qr = s2;     // col l+|m|
        if (col == l + m) qi = -s2;    // col l-|m|
    } else if (m == 0) {
        if (col == l) qr = 1.0;
    } else {
        double sg = (m & 1) ? -1.0 : 1.0;
        if (col == l + m) qr = sg * s2;
        if (col == l - m) qi = sg * s2;
    }
    double rr, ii;
    switch (l & 3) {                  // multiply by (-i)^l
        case 0:  rr = qr;  ii = qi;  break;
        case 1:  rr = qi;  ii = -qr; break;
        case 2:  rr = -qr; ii = -qi; break;
        default: rr = -qi; ii = qr;  break;
    }
    *pre = rr; *pim = ii;
}

// ---------------------------------------------------------------------------
__global__ __launch_bounds__(256) void sh_init_kernel(float* __restrict__ cgws,
                                                      int4* __restrict__ jobs) {
    int blk = blockIdx.x;
    if (blk < 27) {
        // find blk-th cg term
        int t = 0, cnt = -1;
        for (t = 0; t < 34; ++t) { if (T_cg[t] >= 0) { ++cnt; if (cnt == blk) break; } }
        int j1 = T_j[t], j2 = T_l[t], j3 = T_J[t], off = T_cg[t];
        int d1 = 2 * j1 + 1, d2 = 2 * j2 + 1, d3 = 2 * j3 + 1;
        int tot = d1 * d2 * d3;
        for (int e = threadIdx.x; e < tot; e += blockDim.x) {
            int a  = e / (d2 * d3);
            int b2 = (e / d3) % d2;
            int cp = e % d3;
            double re = 0.0;
            for (int i = 0; i < d1; ++i) {
                for (int k = 0; k < d2; ++k) {
                    int m1 = i - j1, m2 = k - j2, m3 = m1 + m2;
                    if (m3 < -j3 || m3 > j3) continue;
                    double cg = su2cg(j1, m1, j2, m2, j3, m3);
                    if (cg == 0.0) continue;
                    double q1r, q1i, q2r, q2i, q3r, q3i;
                    qelem(j1, i, a, &q1r, &q1i);
                    qelem(j2, k, b2, &q2r, &q2i);
                    qelem(j3, j3 + m3, cp, &q3r, &q3i);
                    q3i = -q3i;  // conj
                    double pr = q1r * q2r - q1i * q2i;
                    double pi = q1r * q2i + q1i * q2r;
                    double rr = pr * q3r - pi * q3i;  // real part of (q1 q2 conj(q3))
                    re += rr * cg;
                }
            }
            float val = (fabs(re) < 1e-12) ? 0.f : (float)re;
            cgws[off + (a * d2 + b2) * d3 + cp] = val;
        }
    } else {
        if (threadIdx.x == 0) cgws[CG_ONE] = 1.0f;
        for (int jid = threadIdx.x; jid < NJOBS; jid += blockDim.x) {
            // locate term
            int t = 0, q = jid;
            for (;;) {
                int npt = (2 * T_J[t] + 1) * (4 - T_j[t]) * 4;
                if (q < npt) break;
                q -= npt; ++t;
            }
            int J = T_J[t], j = T_j[t], l = T_l[t], choff = T_ch[t], cgo = T_cg[t];
            int rc = (4 - j) * 4;
            int p = q / rc;
            int rem = q % rc;
            int r = rem >> 2, c4 = rem & 3;
            int out_const = OTAB[J] + p * WTAB[J] + choff + r * 16 + c4 * 4;
            int y_base, cg_off, nj, nl;
            if (cgo == -1) {                       // l0 copy: j = J, l = 0
                y_base = (YOFF[j] + p * (4 - j) + r) * YS + c4 * 4;
                cg_off = CG_ONE; nj = 1; nl = 1;
            } else if (cgo == -2) {                // j0 copy: j = 0, l = J
                y_base = r * YS + COFF[l] + p * 16 + c4 * 4;
                cg_off = CG_ONE; nj = 1; nl = 1;
            } else {                               // cg term
                y_base = (YOFF[j] + r) * YS + COFF[l] + c4 * 4;
                cg_off = cgo + p; nj = 2 * j + 1; nl = 2 * l + 1;
            }
            int packed = nj | (nl << 8) | (J << 16);
            jobs[jid] = make_int4(out_const, y_base, cg_off, packed);
        }
    }
}

// ---------------------------------------------------------------------------
__global__ __launch_bounds__(256) void sh_conv_kernel(
    const float* __restrict__ x0, const float* __restrict__ x1,
    const float* __restrict__ x2, const float* __restrict__ x3,
    const int* __restrict__ pidx, const float* __restrict__ kern,
    const float* __restrict__ cgws, const int4* __restrict__ jobs,
    float* __restrict__ out) {
    __shared__ __align__(16) float Gbuf[8192];   // G (32x256) then y (30 x YS)
    __shared__ int nbr[NP];

    const int bv = blockIdx.x;
    const int tid = threadIdx.x;

    if (tid < NP) {
        int bi = pidx[(bv * NP + tid) * 2 + 0];
        int ni = pidx[(bv * NP + tid) * 2 + 1];
        nbr[tid] = bi * NN + ni;
    }
    __syncthreads();

    // ---- phase 0: gather G into LDS (float4 per lane) ----
    {
        const int c4 = tid & 63;
        const int psub = tid >> 6;
        const int c = c4 * 4;
        for (int it = 0; it < 8; ++it) {
            int p = it * 4 + psub;
            int row = nbr[p];
            float4 v;
            if (c < 16)        v = *(const float4*)(x0 + row * 16 + c);
            else if (c < 64)   v = *(const float4*)(x1 + row * 48 + (c - 16));
            else if (c < 144)  v = *(const float4*)(x2 + row * 80 + (c - 64));
            else               v = *(const float4*)(x3 + row * 112 + (c - 144));
            *(float4*)(&Gbuf[p * NCH + c]) = v;
        }
    }
    __syncthreads();

    // ---- phase 1: y = K^T G. thread = one column (tid), all 30 rows ----
    float acc[NY];
#pragma unroll
    for (int r = 0; r < NY; ++r) acc[r] = 0.f;
    const float* kb = kern + (size_t)bv * (NP * NY);   // block-uniform -> s_load
    const int c = tid;
    for (int p = 0; p < NP; ++p) {
        float g = Gbuf[p * NCH + c];
#pragma unroll
        for (int r = 0; r < NY; ++r) acc[r] = fmaf(kb[p * NY + r], g, acc[r]);
    }
    __syncthreads();   // everyone done reading G

    // ---- phase 2: y -> LDS with padded stride ----
#pragma unroll
    for (int r = 0; r < NY; ++r) Gbuf[r * YS + c] = acc[r];
    __syncthreads();

    // ---- phase 3: jobs (one float4 of output each) ----
    for (int jid = tid; jid < NJOBS; jid += 256) {
        int4 jb = jobs[jid];
        int out_const = jb.x, y_base = jb.y, cg_off = jb.z, packed = jb.w;
        int nj = packed & 255, nl = (packed >> 8) & 255, J = (packed >> 16) & 255;
        int dJ = 2 * J + 1;
        int jj = (nj - 1) >> 1;
        int nstr = (4 - jj) * YS;
        float4 s = {0.f, 0.f, 0.f, 0.f};
        int idx = cg_off;
        for (int a = 0; a < nj; ++a) {
            int yb = y_base + a * nstr;
            for (int b2 = 0; b2 < nl; ++b2) {
                float coeff = cgws[idx];
                idx += dJ;
                if (coeff != 0.f) {
                    float4 yv = *(const float4*)(&Gbuf[yb + b2 * 16]);
                    s.x = fmaf(coeff, yv.x, s.x);
                    s.y = fmaf(coeff, yv.y, s.y);
                    s.z = fmaf(coeff, yv.z, s.z);
                    s.w = fmaf(coeff, yv.w, s.w);
                }
            }
        }
        float* dst = out + (size_t)out_const + (size_t)bv * STAB[J];
        *(float4*)dst = s;
    }
}

// ---------------------------------------------------------------------------
extern "C" void kernel_launch(void* const* d_in, const int* in_sizes, int n_in,
                              void* d_out, int out_size, void* d_ws, size_t ws_size,
                              hipStream_t stream) {
    const float* x0 = (const float*)d_in[0];
    const float* x1 = (const float*)d_in[1];
    const float* x2 = (const float*)d_in[2];
    const float* x3 = (const float*)d_in[3];
    const int* pidx = (const int*)d_in[4];
    const float* kern = (const float*)d_in[5];

    float* cgws = (float*)d_ws;
    int4* jobs = (int4*)((char*)d_ws + JOBS_BYTE_OFF);

    sh_init_kernel<<<28, 256, 0, stream>>>(cgws, jobs);
    sh_conv_kernel<<<NB * NV, 256, 0, stream>>>(x0, x1, x2, x3, pidx, kern,
                                                cgws, jobs, (float*)d_out);
}

// Round 3
// 484.562 us; speedup vs baseline: 1.6628x; 1.6628x over previous
//
#include <hip/hip_runtime.h>

// ---------------------------------------------------------------------------
// SphericalHarmonicsShellsConv  (MI355X / gfx950) — round 3 (r2 + NT-store fix)
//
// Per (b,v):  y(30x256) = K^T(30x32) · G(32x256) gathered  ->  CG recombine.
//
// conv_kernel (8192 blocks x 256): thread = one channel column c.
//   GEMM: g loaded DIRECTLY from global (coalesced; rows via s_load'd pidx),
//         K via block-uniform s_loads. acc[30] in VGPRs.
//   y -> LDS (stride 260), one barrier, then compact-list CG jobs
//   (each job = one output float4; inner loop over nnz {y_off, coeff}).
// init: kernel A (27 blocks, fp32+factorial LUT) builds dense CG tables;
//       kernel B (1 block) compacts nnz lists + builds 1332 job records.
// ---------------------------------------------------------------------------

#define NB      4
#define NN      4096
#define NV      2048
#define NP      32
#define NCH     256
#define NY      30
#define YS      260          // padded row stride for y in LDS (floats)
#define NJOBS   1332
#define CG_ONE  3269         // list slot holding the single {0, 1.0f} copy entry
#define LISTS_OFF 13088      // 3269*4 -> 16-aligned
#define JOBS_OFF  39248      // LISTS_OFF + 3270*8

typedef float  f32x4 __attribute__((ext_vector_type(4)));   // native vec for NT store

// ---- term tables (34 terms) ------------------------------------------------
// cg = -1: l0 copy (j=J,l=0); cg = -2: j0 copy (j=0,l=J); else offset in cgws
__device__ const int T_J[34]  = {0,0,0,0, 1,1,1,1,1,1,1,1,1, 2,2,2,2,2,2,2,2,2,2,2, 3,3,3,3,3,3,3,3,3,3};
__device__ const int T_j[34]  = {0,1,2,3, 1,0,1,2,1,2,3,2,3, 2,0,1,2,3,1,2,3,1,2,3, 3,0,2,3,1,2,3,1,2,3};
__device__ const int T_l[34]  = {0,1,2,3, 0,1,1,1,2,2,2,3,3, 0,2,1,1,1,2,2,2,3,3,3, 0,3,1,1,2,2,2,3,3,3};
__device__ const int T_ch[34] = {0,64,112,144, 0,48,112,160,192,240,272,288,320,
                                 0,32,96,144,176,192,240,272,288,336,368,
                                 0,16,80,112,128,176,208,224,272,304};
__device__ const int T_cg[34] = {-1,0,9,34, -1,-2,83,110,155,200,275,380,485,
                                 -1,-2,632,677,752,857,932,1057,1232,1337,1512,
                                 -1,-2,1757,1862,2009,2114,2289,2534,2681,2926};

__device__ const int YOFF[4] = {0, 4, 13, 23};
__device__ const int COFF[4] = {0, 16, 64, 144};
__device__ const int WTAB[4] = {160, 336, 384, 320};
__device__ const int OTAB[4] = {0, 1310720, 9568256, 25296896};

// factorials 0..10 (all exact in fp32, < 2^24)
__device__ const float FACT[11] = {1.f,1.f,2.f,6.f,24.f,120.f,720.f,5040.f,
                                   40320.f,362880.f,3628800.f};

// ---------------------------------------------------------------------------
__device__ float su2cgf(int j1, int m1, int j2, int m2, int j3, int m3) {
    int vmin = -j1 + j2 + m3;
    if (-j1 + m1 > vmin) vmin = -j1 + m1;
    if (0 > vmin) vmin = 0;
    int vmax = j2 + j3 + m1;
    if (j3 - j1 + j2 < vmax) vmax = j3 - j1 + j2;
    if (j3 + m3 < vmax) vmax = j3 + m3;
    float num = (2.f * j3 + 1.f) * FACT[j3 + j1 - j2] * FACT[j3 - j1 + j2] *
                FACT[j1 + j2 - j3] * FACT[j3 + m3] * FACT[j3 - m3];
    float den = FACT[j1 + j2 + j3 + 1] * FACT[j1 - m1] * FACT[j1 + m1] *
                FACT[j2 - m2] * FACT[j2 + m2];
    float Cc = sqrtf(num / den);
    float S = 0.f;
    for (int v = vmin; v <= vmax; ++v) {
        float t = FACT[j2 + j3 + m1 - v] * FACT[j1 - m1 + v] /
                  (FACT[v] * FACT[j3 - j1 + j2 - v] * FACT[j3 + m3 - v] *
                   FACT[v + j1 - j2 - m3]);
        S += ((v + j2 + m2) & 1) ? -t : t;
    }
    return Cc * S;
}

// element [row][col] of (-i)^l * q_real_to_complex(l), fp32
__device__ void qelemf(int l, int row, int col, float* pre, float* pim) {
    int m = row - l;
    const float s2 = 0.70710678118654752440f;
    float qr = 0.f, qi = 0.f;
    if (m < 0) {
        if (col == l - m) qr = s2;
        if (col == l + m) qi = -s2;
    } else if (m == 0) {
        if (col == l) qr = 1.f;
    } else {
        float sg = (m & 1) ? -1.f : 1.f;
        if (col == l + m) qr = sg * s2;
        if (col == l - m) qi = sg * s2;
    }
    float rr, ii;
    switch (l & 3) {
        case 0:  rr = qr;  ii = qi;  break;
        case 1:  rr = qi;  ii = -qr; break;
        case 2:  rr = -qr; ii = -qi; break;
        default: rr = -qi; ii = qr;  break;
    }
    *pre = rr; *pim = ii;
}

// ---------------------------------------------------------------------------
// kernel A: dense real-CG tables (27 blocks; block k = k-th cg term)
__global__ __launch_bounds__(256) void sh_cg_kernel(float* __restrict__ cgws) {
    int k = blockIdx.x;
    int t = 0, seen = -1;
    for (t = 0; t < 34; ++t) { if (T_cg[t] >= 0) { ++seen; if (seen == k) break; } }
    int j1 = T_j[t], j2 = T_l[t], j3 = T_J[t], off = T_cg[t];
    int d1 = 2 * j1 + 1, d2 = 2 * j2 + 1, d3 = 2 * j3 + 1;
    int tot = d1 * d2 * d3;
    for (int e = threadIdx.x; e < tot; e += blockDim.x) {
        int a  = e / (d2 * d3);
        int b2 = (e / d3) % d2;
        int cp = e % d3;
        float re = 0.f;
        for (int i = 0; i < d1; ++i) {
            for (int kk = 0; kk < d2; ++kk) {
                int m1 = i - j1, m2 = kk - j2, m3 = m1 + m2;
                if (m3 < -j3 || m3 > j3) continue;
                float cg = su2cgf(j1, m1, j2, m2, j3, m3);
                if (cg == 0.f) continue;
                float q1r, q1i, q2r, q2i, q3r, q3i;
                qelemf(j1, i, a, &q1r, &q1i);
                qelemf(j2, kk, b2, &q2r, &q2i);
                qelemf(j3, j3 + m3, cp, &q3r, &q3i);
                q3i = -q3i;  // conj
                float pr = q1r * q2r - q1i * q2i;
                float pi = q1r * q2i + q1i * q2r;
                re += (pr * q3r - pi * q3i) * cg;
            }
        }
        float val = (fabsf(re) < 1e-4f) ? 0.f : re;
        cgws[off + (a * d2 + b2) * d3 + cp] = val;
    }
}

// ---------------------------------------------------------------------------
// kernel B: compact nnz lists per (cg-term, m3) + 1332 job records (1 block)
__global__ __launch_bounds__(256) void sh_tab_kernel(const float* __restrict__ cgws,
                                                     int2* __restrict__ lists,
                                                     int4* __restrict__ jobs) {
    __shared__ int cnts[27 * 7];
    int tid = threadIdx.x;
    if (tid == 0) lists[CG_ONE] = make_int2(0, __float_as_int(1.0f));
    if (tid < 189) {
        int k = tid / 7, p = tid % 7;
        int t = 0, seen = -1;
        for (t = 0; t < 34; ++t) { if (T_cg[t] >= 0) { ++seen; if (seen == k) break; } }
        int J = T_J[t], j = T_j[t], l = T_l[t];
        int cnt = 0;
        if (p < 2 * J + 1) {
            int base = T_cg[t];
            int dJ = 2 * J + 1, nj = 2 * j + 1, nl = 2 * l + 1;
            int lbase = base + p * nj * nl;
            for (int n = 0; n < nj; ++n)
                for (int m = 0; m < nl; ++m) {
                    float cf = cgws[base + (n * nl + m) * dJ + p];
                    if (cf != 0.f) {
                        lists[lbase + cnt] =
                            make_int2(n * (4 - j) * YS + m * 16, __float_as_int(cf));
                        ++cnt;
                    }
                }
        }
        cnts[k * 7 + p] = cnt;
    }
    __syncthreads();
    for (int jid = tid; jid < NJOBS; jid += 256) {
        int t = 0, q = jid, cgIdx = 0;
        for (;;) {
            int npt = (2 * T_J[t] + 1) * (4 - T_j[t]) * 4;
            if (q < npt) break;
            q -= npt;
            if (T_cg[t] >= 0) ++cgIdx;
            ++t;
        }
        int J = T_J[t], j = T_j[t], l = T_l[t], choff = T_ch[t], cgo = T_cg[t];
        int rc = (4 - j) * 4;
        int p = q / rc;
        int rem = q % rc;
        int r = rem >> 2, c4 = rem & 3;
        int out_off = OTAB[J] + p * WTAB[J] + choff + r * 16 + c4 * 4;
        int y_base, list_off, count;
        if (cgo == -1) {                       // l0 copy: j = J, l = 0
            y_base = (YOFF[j] + p * (4 - j) + r) * YS + c4 * 4;
            list_off = CG_ONE; count = 1;
        } else if (cgo == -2) {                // j0 copy: j = 0, l = J
            y_base = r * YS + COFF[l] + p * 16 + c4 * 4;
            list_off = CG_ONE; count = 1;
        } else {
            y_base = (YOFF[j] + r) * YS + COFF[l] + c4 * 4;
            list_off = cgo + p * (2 * j + 1) * (2 * l + 1);
            count = cnts[cgIdx * 7 + p];
        }
        jobs[jid] = make_int4(out_off | (J << 28), y_base, list_off, count);
    }
}

// ---------------------------------------------------------------------------
__global__ __launch_bounds__(256) void sh_conv_kernel(
    const float* __restrict__ x0, const float* __restrict__ x1,
    const float* __restrict__ x2, const float* __restrict__ x3,
    const int* __restrict__ pidx, const float* __restrict__ kern,
    const int2* __restrict__ lists, const int4* __restrict__ jobs,
    float* __restrict__ out) {
    __shared__ __align__(16) float Y[NY * YS];   // 31200 B -> 5 blocks/CU

    const int bv = blockIdx.x;
    const int c = threadIdx.x;

    // per-thread gather source (fixed per column)
    const float* src; int stride;
    if (c < 16)       { src = x0 + c;         stride = 16;  }
    else if (c < 64)  { src = x1 + (c - 16);  stride = 48;  }
    else if (c < 144) { src = x2 + (c - 64);  stride = 80;  }
    else              { src = x3 + (c - 144); stride = 112; }

    const float* kb = kern + (size_t)bv * (NP * NY);   // block-uniform -> s_load
    const int*   pp = pidx + (size_t)bv * (NP * 2);    // block-uniform -> s_load

    // ---- GEMM: y[r][c] = sum_p K[p][r] * G[p][c], G straight from global ----
    float acc[NY];
#pragma unroll
    for (int r = 0; r < NY; ++r) acc[r] = 0.f;

#pragma unroll
    for (int pg = 0; pg < 4; ++pg) {
        float g[8];
#pragma unroll
        for (int u = 0; u < 8; ++u) {
            int p = pg * 8 + u;
            int row = pp[2 * p] * NN + pp[2 * p + 1];
            g[u] = src[(size_t)row * stride];
        }
#pragma unroll
        for (int u = 0; u < 8; ++u) {
            int p = pg * 8 + u;
#pragma unroll
            for (int r = 0; r < NY; ++r)
                acc[r] = fmaf(kb[p * NY + r], g[u], acc[r]);
        }
    }

    // ---- y -> LDS (stride-1 across lanes: conflict-free) ----
#pragma unroll
    for (int r = 0; r < NY; ++r) Y[r * YS + c] = acc[r];
    __syncthreads();

    // ---- CG jobs: one output float4 each, compact nnz list ----
    const int s0 = bv * 160, s1 = bv * 1008, s2 = bv * 1920, s3 = bv * 2240;
    for (int jid = c; jid < NJOBS; jid += 256) {
        int4 jb = jobs[jid];
        int J = ((unsigned)jb.x) >> 28;
        int out_off = jb.x & 0x0FFFFFFF;
        int bvoff = (J < 2) ? (J == 0 ? s0 : s1) : (J == 2 ? s2 : s3);
        const int2* lp = lists + jb.z;
        const float* yb = &Y[jb.y];
        f32x4 s = {0.f, 0.f, 0.f, 0.f};
        for (int e = 0; e < jb.w; ++e) {
            int2 en = lp[e];
            float cf = __int_as_float(en.y);
            const f32x4 yv = *(const f32x4*)(yb + en.x);
            s.x = fmaf(cf, yv.x, s.x);
            s.y = fmaf(cf, yv.y, s.y);
            s.z = fmaf(cf, yv.z, s.z);
            s.w = fmaf(cf, yv.w, s.w);
        }
        __builtin_nontemporal_store(s, (f32x4*)(out + (size_t)out_off + bvoff));
    }
}

// ---------------------------------------------------------------------------
extern "C" void kernel_launch(void* const* d_in, const int* in_sizes, int n_in,
                              void* d_out, int out_size, void* d_ws, size_t ws_size,
                              hipStream_t stream) {
    const float* x0 = (const float*)d_in[0];
    const float* x1 = (const float*)d_in[1];
    const float* x2 = (const float*)d_in[2];
    const float* x3 = (const float*)d_in[3];
    const int* pidx = (const int*)d_in[4];
    const float* kern = (const float*)d_in[5];

    float* cgws = (float*)d_ws;
    int2* lists = (int2*)((char*)d_ws + LISTS_OFF);
    int4* jobs  = (int4*)((char*)d_ws + JOBS_OFF);

    sh_cg_kernel<<<27, 256, 0, stream>>>(cgws);
    sh_tab_kernel<<<1, 256, 0, stream>>>(cgws, lists, jobs);
    sh_conv_kernel<<<NB * NV, 256, 0, stream>>>(x0, x1, x2, x3, pidx, kern,
                                                lists, jobs, (float*)d_out);
}

// Round 4
// 421.537 us; speedup vs baseline: 1.9114x; 1.1495x over previous
//
#include <hip/hip_runtime.h>

// ---------------------------------------------------------------------------
// SphericalHarmonicsShellsConv  (MI355X / gfx950) — round 4
//
// Per (b,v):  y(30x256) = K^T(30x32) · G(32x256) gathered  ->  CG recombine.
//
// conv_kernel (8192 blocks x 256, 8 blocks/CU): thread = one channel column.
//   GEMM from global (coalesced; rows via s_load'd pidx; K block-uniform).
//   Copy outputs (l=0 / j=0 slices, 1440 floats/bv) stored DIRECTLY from
//   registers in fp32 before the barrier.
//   cg part: y rows 4..29 x cols 16..255 -> LDS as bf16 (26x244 u16, 12.7KB),
//   one barrier, 972 jobs (one output float4 each; compact nnz lists).
// ---------------------------------------------------------------------------

#define NB      4
#define NN      4096
#define NV      2048
#define NP      32
#define NY      30
#define YROWS   26
#define YCOLS   244          // u16 row stride (240 cols + 4 pad)
#define NJOBS_CG 972
#define LISTS_OFF 13088      // 3269*4 -> 16-aligned
#define JOBS_OFF  39248      // LISTS_OFF + 3270*8

typedef float f32x4 __attribute__((ext_vector_type(4)));

// ---- term tables (34 terms) ------------------------------------------------
// cg = -1: l0 copy (j=J,l=0); cg = -2: j0 copy (j=0,l=J); else offset in cgws
__device__ const int T_J[34]  = {0,0,0,0, 1,1,1,1,1,1,1,1,1, 2,2,2,2,2,2,2,2,2,2,2, 3,3,3,3,3,3,3,3,3,3};
__device__ const int T_j[34]  = {0,1,2,3, 1,0,1,2,1,2,3,2,3, 2,0,1,2,3,1,2,3,1,2,3, 3,0,2,3,1,2,3,1,2,3};
__device__ const int T_l[34]  = {0,1,2,3, 0,1,1,1,2,2,2,3,3, 0,2,1,1,1,2,2,2,3,3,3, 0,3,1,1,2,2,2,3,3,3};
__device__ const int T_ch[34] = {0,64,112,144, 0,48,112,160,192,240,272,288,320,
                                 0,32,96,144,176,192,240,272,288,336,368,
                                 0,16,80,112,128,176,208,224,272,304};
__device__ const int T_cg[34] = {-1,0,9,34, -1,-2,83,110,155,200,275,380,485,
                                 -1,-2,632,677,752,857,932,1057,1232,1337,1512,
                                 -1,-2,1757,1862,2009,2114,2289,2534,2681,2926};

__device__ const int YOFF[4]  = {0, 4, 13, 23};
__device__ const int YOFFP[4] = {0, 0, 9, 19};    // row base in reduced Y (j>=1)
__device__ const int COFF[4]  = {0, 16, 64, 144};
__device__ const int WTAB[4]  = {160, 336, 384, 320};
__device__ const int OTAB[4]  = {0, 1310720, 9568256, 25296896};

__device__ const float FACT[11] = {1.f,1.f,2.f,6.f,24.f,120.f,720.f,5040.f,
                                   40320.f,362880.f,3628800.f};

// ---------------------------------------------------------------------------
__device__ float su2cgf(int j1, int m1, int j2, int m2, int j3, int m3) {
    int vmin = -j1 + j2 + m3;
    if (-j1 + m1 > vmin) vmin = -j1 + m1;
    if (0 > vmin) vmin = 0;
    int vmax = j2 + j3 + m1;
    if (j3 - j1 + j2 < vmax) vmax = j3 - j1 + j2;
    if (j3 + m3 < vmax) vmax = j3 + m3;
    float num = (2.f * j3 + 1.f) * FACT[j3 + j1 - j2] * FACT[j3 - j1 + j2] *
                FACT[j1 + j2 - j3] * FACT[j3 + m3] * FACT[j3 - m3];
    float den = FACT[j1 + j2 + j3 + 1] * FACT[j1 - m1] * FACT[j1 + m1] *
                FACT[j2 - m2] * FACT[j2 + m2];
    float Cc = sqrtf(num / den);
    float S = 0.f;
    for (int v = vmin; v <= vmax; ++v) {
        float t = FACT[j2 + j3 + m1 - v] * FACT[j1 - m1 + v] /
                  (FACT[v] * FACT[j3 - j1 + j2 - v] * FACT[j3 + m3 - v] *
                   FACT[v + j1 - j2 - m3]);
        S += ((v + j2 + m2) & 1) ? -t : t;
    }
    return Cc * S;
}

__device__ void qelemf(int l, int row, int col, float* pre, float* pim) {
    int m = row - l;
    const float s2 = 0.70710678118654752440f;
    float qr = 0.f, qi = 0.f;
    if (m < 0) {
        if (col == l - m) qr = s2;
        if (col == l + m) qi = -s2;
    } else if (m == 0) {
        if (col == l) qr = 1.f;
    } else {
        float sg = (m & 1) ? -1.f : 1.f;
        if (col == l + m) qr = sg * s2;
        if (col == l - m) qi = sg * s2;
    }
    float rr, ii;
    switch (l & 3) {
        case 0:  rr = qr;  ii = qi;  break;
        case 1:  rr = qi;  ii = -qr; break;
        case 2:  rr = -qr; ii = -qi; break;
        default: rr = -qi; ii = qr;  break;
    }
    *pre = rr; *pim = ii;
}

__device__ inline unsigned short f2bf(float x) {   // RNE
    unsigned u = __float_as_uint(x);
    return (unsigned short)((u + 0x7fffu + ((u >> 16) & 1u)) >> 16);
}

// ---------------------------------------------------------------------------
// kernel A: dense real-CG tables (27 blocks; block k = k-th cg term)
__global__ __launch_bounds__(256) void sh_cg_kernel(float* __restrict__ cgws) {
    int k = blockIdx.x;
    int t = 0, seen = -1;
    for (t = 0; t < 34; ++t) { if (T_cg[t] >= 0) { ++seen; if (seen == k) break; } }
    int j1 = T_j[t], j2 = T_l[t], j3 = T_J[t], off = T_cg[t];
    int d1 = 2 * j1 + 1, d2 = 2 * j2 + 1, d3 = 2 * j3 + 1;
    int tot = d1 * d2 * d3;
    for (int e = threadIdx.x; e < tot; e += blockDim.x) {
        int a  = e / (d2 * d3);
        int b2 = (e / d3) % d2;
        int cp = e % d3;
        float re = 0.f;
        for (int i = 0; i < d1; ++i) {
            for (int kk = 0; kk < d2; ++kk) {
                int m1 = i - j1, m2 = kk - j2, m3 = m1 + m2;
                if (m3 < -j3 || m3 > j3) continue;
                float cg = su2cgf(j1, m1, j2, m2, j3, m3);
                if (cg == 0.f) continue;
                float q1r, q1i, q2r, q2i, q3r, q3i;
                qelemf(j1, i, a, &q1r, &q1i);
                qelemf(j2, kk, b2, &q2r, &q2i);
                qelemf(j3, j3 + m3, cp, &q3r, &q3i);
                q3i = -q3i;
                float pr = q1r * q2r - q1i * q2i;
                float pi = q1r * q2i + q1i * q2r;
                re += (pr * q3r - pi * q3i) * cg;
            }
        }
        float val = (fabsf(re) < 1e-4f) ? 0.f : re;
        cgws[off + (a * d2 + b2) * d3 + cp] = val;
    }
}

// ---------------------------------------------------------------------------
// kernel B: compact nnz lists per (cg-term, m3) + 972 cg-job records (1 block)
__global__ __launch_bounds__(256) void sh_tab_kernel(const float* __restrict__ cgws,
                                                     int2* __restrict__ lists,
                                                     int4* __restrict__ jobs) {
    __shared__ int cnts[27 * 7];
    int tid = threadIdx.x;
    if (tid < 189) {
        int k = tid / 7, p = tid % 7;
        int t = 0, seen = -1;
        for (t = 0; t < 34; ++t) { if (T_cg[t] >= 0) { ++seen; if (seen == k) break; } }
        int J = T_J[t], j = T_j[t], l = T_l[t];
        int cnt = 0;
        if (p < 2 * J + 1) {
            int base = T_cg[t];
            int dJ = 2 * J + 1, nj = 2 * j + 1, nl = 2 * l + 1;
            int lbase = base + p * nj * nl;
            for (int n = 0; n < nj; ++n)
                for (int m = 0; m < nl; ++m) {
                    float cf = cgws[base + (n * nl + m) * dJ + p];
                    if (cf != 0.f) {
                        // offset in u16 units within reduced bf16 Y
                        lists[lbase + cnt] =
                            make_int2(n * (4 - j) * YCOLS + m * 16, __float_as_int(cf));
                        ++cnt;
                    }
                }
        }
        cnts[k * 7 + p] = cnt;
    }
    __syncthreads();
    for (int jid = tid; jid < NJOBS_CG; jid += 256) {
        int t = 0, q = jid, cgIdx = -1;
        for (t = 0; t < 34; ++t) {
            if (T_cg[t] < 0) continue;
            ++cgIdx;
            int npt = (2 * T_J[t] + 1) * (4 - T_j[t]) * 4;
            if (q < npt) break;
            q -= npt;
        }
        int J = T_J[t], j = T_j[t], l = T_l[t];
        int rc = (4 - j) * 4;
        int p = q / rc;
        int rem = q % rc;
        int r = rem >> 2, c4 = rem & 3;
        int out_off = OTAB[J] + p * WTAB[J] + T_ch[t] + r * 16 + c4 * 4;
        int y_base = (YOFFP[j] + r) * YCOLS + (COFF[l] - 16) + c4 * 4;  // u16 units
        int list_off = T_cg[t] + p * (2 * j + 1) * (2 * l + 1);
        int count = cnts[cgIdx * 7 + p];
        jobs[jid] = make_int4(out_off | (J << 28), y_base, list_off, count);
    }
}

// ---------------------------------------------------------------------------
__global__ __launch_bounds__(256, 8) void sh_conv_kernel(
    const float* __restrict__ x0, const float* __restrict__ x1,
    const float* __restrict__ x2, const float* __restrict__ x3,
    const int* __restrict__ pidx, const float* __restrict__ kern,
    const int2* __restrict__ lists, const int4* __restrict__ jobs,
    float* __restrict__ out) {
    __shared__ __align__(8) unsigned short Y16[YROWS * YCOLS];  // 12688 B

    const int bv = blockIdx.x;
    const int c = threadIdx.x;

    // per-thread gather source (fixed per column)
    const float* src; int stride;
    if (c < 16)       { src = x0 + c;         stride = 16;  }
    else if (c < 64)  { src = x1 + (c - 16);  stride = 48;  }
    else if (c < 144) { src = x2 + (c - 64);  stride = 80;  }
    else              { src = x3 + (c - 144); stride = 112; }

    const float* kb = kern + (size_t)bv * (NP * NY);   // block-uniform -> s_load
    const int*   pp = pidx + (size_t)bv * (NP * 2);    // block-uniform -> s_load

    // ---- GEMM: y[r][c] = sum_p K[p][r] * G[p][c], G straight from global ----
    float acc[NY];
#pragma unroll
    for (int r = 0; r < NY; ++r) acc[r] = 0.f;

#pragma unroll
    for (int pg = 0; pg < 4; ++pg) {
        float g[8];
#pragma unroll
        for (int u = 0; u < 8; ++u) {
            int p = pg * 8 + u;
            int row = pp[2 * p] * NN + pp[2 * p + 1];
            g[u] = src[(size_t)row * stride];
        }
#pragma unroll
        for (int u = 0; u < 8; ++u) {
            int p = pg * 8 + u;
#pragma unroll
            for (int r = 0; r < NY; ++r)
                acc[r] = fmaf(kb[p * NY + r], g[u], acc[r]);
        }
    }

    const int sJ0 = bv * 160, sJ1 = bv * 1008, sJ2 = bv * 1920, sJ3 = bv * 2240;

    // ---- direct copy outputs from registers (fp32) ----
    if (c < 16) {
        // l0 copies: out[J=j], channel block 0, all 30 rows of this column
#pragma unroll
        for (int j = 0; j < 4; ++j) {
            int sj = (j < 2) ? (j == 0 ? sJ0 : sJ1) : (j == 2 ? sJ2 : sJ3);
            float* ob = out + (size_t)OTAB[j] + sj + c;
#pragma unroll
            for (int p = 0; p < 2 * j + 1; ++p)
#pragma unroll
                for (int r = 0; r < 4 - j; ++r)
                    __builtin_nontemporal_store(
                        acc[YOFF[j] + p * (4 - j) + r],
                        ob + p * WTAB[j] + r * 16);
        }
    } else {
        // j0 copies: rows 0..3 of this column -> out[J=l]
        int l = (c < 64) ? 1 : (c < 144 ? 2 : 3);
        int sj = (l == 1) ? sJ1 : (l == 2 ? sJ2 : sJ3);
        int chj0 = (l == 1) ? 48 : (l == 2 ? 32 : 16);
        int rel = c - COFF[l];
        int m = rel >> 4, ch = rel & 15;
        float* ob = out + (size_t)OTAB[l] + sj + m * WTAB[l] + chj0 + ch;
#pragma unroll
        for (int r = 0; r < 4; ++r)
            __builtin_nontemporal_store(acc[r], ob + r * 16);
    }

    // ---- y rows 4..29, cols 16..255 -> LDS as bf16 ----
    if (c >= 16) {
        int cc = c - 16;
#pragma unroll
        for (int r = 4; r < NY; ++r)
            Y16[(r - 4) * YCOLS + cc] = f2bf(acc[r]);
    }
    __syncthreads();

    // ---- cg jobs: one output float4 each, compact nnz list, bf16 y ----
    for (int jid = c; jid < NJOBS_CG; jid += 256) {
        int4 jb = jobs[jid];
        int J = ((unsigned)jb.x) >> 28;
        int out_off = jb.x & 0x0FFFFFFF;
        int bvoff = (J < 2) ? (J == 0 ? sJ0 : sJ1) : (J == 2 ? sJ2 : sJ3);
        const int2* lp = lists + jb.z;
        const unsigned short* yb = &Y16[jb.y];
        f32x4 s = {0.f, 0.f, 0.f, 0.f};
        for (int e = 0; e < jb.w; ++e) {
            int2 en = lp[e];
            float cf = __int_as_float(en.y);
            uint2 u = *(const uint2*)(yb + en.x);   // 4 bf16, 8B-aligned
            float y0 = __uint_as_float(u.x << 16);
            float y1 = __uint_as_float(u.x & 0xffff0000u);
            float y2 = __uint_as_float(u.y << 16);
            float y3 = __uint_as_float(u.y & 0xffff0000u);
            s.x = fmaf(cf, y0, s.x);
            s.y = fmaf(cf, y1, s.y);
            s.z = fmaf(cf, y2, s.z);
            s.w = fmaf(cf, y3, s.w);
        }
        __builtin_nontemporal_store(s, (f32x4*)(out + (size_t)out_off + bvoff));
    }
}

// ---------------------------------------------------------------------------
extern "C" void kernel_launch(void* const* d_in, const int* in_sizes, int n_in,
                              void* d_out, int out_size, void* d_ws, size_t ws_size,
                              hipStream_t stream) {
    const float* x0 = (const float*)d_in[0];
    const float* x1 = (const float*)d_in[1];
    const float* x2 = (const float*)d_in[2];
    const float* x3 = (const float*)d_in[3];
    const int* pidx = (const int*)d_in[4];
    const float* kern = (const float*)d_in[5];

    float* cgws = (float*)d_ws;
    int2* lists = (int2*)((char*)d_ws + LISTS_OFF);
    int4* jobs  = (int4*)((char*)d_ws + JOBS_OFF);

    sh_cg_kernel<<<27, 256, 0, stream>>>(cgws);
    sh_tab_kernel<<<1, 256, 0, stream>>>(cgws, lists, jobs);
    sh_conv_kernel<<<NB * NV, 256, 0, stream>>>(x0, x1, x2, x3, pidx, kern,
                                                lists, jobs, (float*)d_out);
}